// Round 3
// baseline (346.289 us; speedup 1.0000x reference)
//
#include <hip/hip_runtime.h>
#include <stdint.h>

#define N_ANCH 25200
#define NCLS   80
#define KSEL   2048
#define MAXDET 1000
#define CONF_T 0.4f
#define IOU_T  0.45f
#define MAX_WH 7680.0f
#define HBINS  512
#define HBASE  0xBE00u
#define NB_RANK 32
#define APB    ((N_ANCH + NB_RANK - 1) / NB_RANK)   // anchors per rank-block

// workspace byte offsets (total 819200 B)
#define WS_KEYS      0        // uint32 [25200]
#define WS_CLS       102400   // int32  [25200]
#define WS_SELSCORE  204800   // float  [2048]
#define WS_SELBOX    212992   // float4 [2048]  (class-offset boxes)
#define WS_DETCAND   245760   // float  [2048*6]
#define WS_MASK      294912   // uint32 MT[64][2048]  (transposed mask)
// ghist (512 u32) aliases the first 2 KB of MT: zeroed by img, filled by
// score, consumed by rank BEFORE mask overwrites the region (stream-ordered).
#define WS_HIST      294912

// ---------------------------------------------------------------- img kernel
__global__ void img_kernel(const int* __restrict__ img, float* __restrict__ xout,
                           uint32_t* __restrict__ ghist) {
    int tid = threadIdx.x;
    if (blockIdx.x == 0 && tid < 256) { ghist[tid] = 0; ghist[tid + 256] = 0; }
    int i = blockIdx.x * 256 + tid;
    if (i >= 640 * 640 * 3) return;
    int c   = i / 409600;
    int rem = i - c * 409600;
    int v = img[rem * 3 + (2 - c)];
    xout[i] = (float)v / 255.0f;
}

// -------------------------------------------------------------- score kernel
// wave-per-anchor: lanes cover the 80 classes with coalesced loads, shuffle
// argmax (first-occurrence tie-break). Lane 0 emits key/cls + LDS histogram.
__global__ void __launch_bounds__(256)
score_kernel(const float* __restrict__ pred0, uint32_t* __restrict__ keys,
             int* __restrict__ cls, uint32_t* __restrict__ ghist) {
    __shared__ uint32_t lh[HBINS];
    int tid = threadIdx.x;
    lh[tid] = 0; lh[tid + 256] = 0;
    __syncthreads();
    int wave = tid >> 6, lane = tid & 63;
    int a0 = (blockIdx.x * 4 + wave) * 64;
    for (int t = 0; t < 64; ++t) {
        int a = a0 + t;
        if (a >= N_ANCH) break;
        const float* p = pred0 + (size_t)a * 85;
        float obj = p[4];
        float v = p[5 + lane] * obj;
        int ci = lane;
        if (lane < 16) {
            float v2 = p[5 + 64 + lane] * obj;
            if (v2 > v) { v = v2; ci = lane + 64; }   // strict > keeps smaller idx
        }
        for (int m = 32; m; m >>= 1) {
            float ov = __shfl_xor(v, m, 64);
            int   oi = __shfl_xor(ci, m, 64);
            if (ov > v || (ov == v && oi < ci)) { v = ov; ci = oi; }
        }
        if (lane == 0) {
            float score = (v > CONF_T) ? v : -1.0f;
            uint32_t bits = __float_as_uint(score);
            uint32_t key = (bits & 0x80000000u) ? ~bits : (bits | 0x80000000u);
            keys[a] = key; cls[a] = ci;
            if (key >= (HBASE << 16)) atomicAdd(&lh[(key >> 16) - HBASE], 1u);
        }
    }
    __syncthreads();
    if (lh[tid])       atomicAdd(&ghist[tid],       lh[tid]);
    if (lh[tid + 256]) atomicAdd(&ghist[tid + 256], lh[tid + 256]);
}

// --------------------------------------------------------------- rank kernel
// 32 blocks. Each: suffix-scan hist -> lim; compact candidates (key,~idx)
// into LDS; for owned candidates (anchor in block's slice), wave-cooperative
// rank = #{strictly greater packs}; write outputs at position = rank.
// No sort anywhere. Output deterministic (rank is absolute).
__global__ void __launch_bounds__(256)
rank_kernel(const uint32_t* __restrict__ keys, const float* __restrict__ pred0,
            const int* __restrict__ cls, const uint32_t* __restrict__ ghist,
            float* __restrict__ sel_score, float4* __restrict__ selbox,
            float* __restrict__ det_cand) {
    __shared__ uint32_t h[HBINS];
    __shared__ unsigned long long s_items[4096];
    __shared__ int s_n;
    __shared__ uint32_t s_lim;
    int tid = threadIdx.x;
    h[tid] = ghist[tid]; h[tid + 256] = ghist[tid + 256];
    if (tid == 0) { s_n = 0; s_lim = (HBASE << 16); }
    __syncthreads();
    // suffix (reverse) inclusive scan, Hillis-Steele, 2 bins/thread
    for (int off = 1; off < HBINS; off <<= 1) {
        uint32_t a0 = h[tid] + ((tid + off < HBINS) ? h[tid + off] : 0u);
        uint32_t a1 = h[tid + 256] + ((tid + 256 + off < HBINS) ? h[tid + 256 + off] : 0u);
        __syncthreads();
        h[tid] = a0; h[tid + 256] = a1;
        __syncthreads();
    }
    for (int b = tid; b < HBINS; b += 256) {
        uint32_t sb  = h[b];
        uint32_t sb1 = (b < HBINS - 1) ? h[b + 1] : 0u;
        if (sb >= KSEL && sb1 < KSEL) s_lim = (uint32_t)(HBASE + b) << 16;
    }
    __syncthreads();
    uint32_t lim = s_lim;

    // compact: vectorized scan of keys (25200 = 6300 uint4)
    const uint4* k4 = (const uint4*)keys;
    for (int i = tid; i < N_ANCH / 4; i += 256) {
        uint4 kk = k4[i];
        uint32_t ks[4] = {kk.x, kk.y, kk.z, kk.w};
        #pragma unroll
        for (int j = 0; j < 4; ++j) {
            if (ks[j] >= lim) {
                int p = atomicAdd(&s_n, 1);
                if (p < 4096)
                    s_items[p] = ((unsigned long long)ks[j] << 32)
                               | (uint32_t)(~(uint32_t)(i * 4 + j));
            }
        }
    }
    __syncthreads();
    int ncand = min(s_n, 4096);
    int wave = tid >> 6, lane = tid & 63;
    int lo = blockIdx.x * APB, hi = lo + APB;
    for (int s = wave; s < ncand; s += 4) {
        unsigned long long item = s_items[s];
        int ai = (int)(~(uint32_t)item);
        if (ai < lo || ai >= hi) continue;
        int c = 0;
        for (int t = lane; t < ncand; t += 64)
            c += (s_items[t] > item) ? 1 : 0;
        for (int m = 32; m; m >>= 1) c += __shfl_xor(c, m, 64);
        if (c < KSEL && lane == 0) {
            uint32_t key = (uint32_t)(item >> 32);
            uint32_t fb = (key & 0x80000000u) ? (key & 0x7FFFFFFFu) : ~key;
            float score = __uint_as_float(fb);
            const float* p = pred0 + (size_t)ai * 85;
            float x = p[0], y = p[1], w = p[2], hh = p[3];
            float x1 = x - w * 0.5f, y1 = y - hh * 0.5f;
            float x2 = x + w * 0.5f, y2 = y + hh * 0.5f;
            float cf = (float)cls[ai];
            float off = cf * MAX_WH;
            selbox[c] = make_float4(x1 + off, y1 + off, x2 + off, y2 + off);
            float* dc = det_cand + (size_t)c * 6;
            dc[0] = x1; dc[1] = y1; dc[2] = x2; dc[3] = y2; dc[4] = score; dc[5] = cf;
            sel_score[c] = score;
        }
    }
}

// --------------------------------------------------------------- mask kernel
// Transposed output MT[w][row]: block covers 256 consecutive rows at fixed w.
// Per-lane reads sx[row] stride-1 (2-way, free); sx[j] broadcast (free).
// Writes coalesced.
__global__ void __launch_bounds__(256)
mask_kernel(const float4* __restrict__ selbox, uint32_t* __restrict__ MT) {
    __shared__ float sx1[KSEL], sy1[KSEL], sx2[KSEL], sy2[KSEL];
    for (int i = threadIdx.x; i < KSEL; i += 256) {
        float4 b = selbox[i];
        sx1[i] = b.x; sy1[i] = b.y; sx2[i] = b.z; sy2[i] = b.w;
    }
    __syncthreads();
    int t = blockIdx.x * 256 + threadIdx.x;
    int row = t & 2047;
    int w   = t >> 11;
    float ax1 = sx1[row], ay1 = sy1[row], ax2 = sx2[row], ay2 = sy2[row];
    float areaA = (ax2 - ax1) * (ay2 - ay1);
    uint32_t bits = 0;
    int jbase = w * 32;
    for (int b = 0; b < 32; ++b) {
        int j = jbase + b;
        if (j > row) {
            float bx1 = sx1[j], by1 = sy1[j], bx2 = sx2[j], by2 = sy2[j];
            float lx = fmaxf(ax1, bx1), ly = fmaxf(ay1, by1);
            float rx = fminf(ax2, bx2), ry = fminf(ay2, by2);
            float ww = fmaxf(rx - lx, 0.0f), hh = fmaxf(ry - ly, 0.0f);
            float inter = ww * hh;
            float areaB = (bx2 - bx1) * (by2 - by1);
            float iou = inter / (areaA + areaB - inter + 1e-7f);
            if (iou > IOU_T) bits |= (1u << b);
        }
    }
    MT[t] = bits;   // t == w*2048 + row
}

// ---------------------------------------------------------------- nms kernel
// One wave. Lane l owns rows [32l,32l+32) keep-bits. Chunk c = rows
// [32c,32c+32): lane loads MT[lane][32c..+32) as 8x uint4 (contiguous).
// 4-buffer software pipeline keeps 3 chunks in flight.
#define NMS_LOAD(BUF, CC) do { \
    _Pragma("unroll") for (int k8 = 0; k8 < 8; ++k8) BUF[k8] = mbase[(CC) * 8 + k8]; \
} while (0)
#define NMS_PROC(BUF, CC) do { \
    uint32_t rw[32]; \
    _Pragma("unroll") for (int k8 = 0; k8 < 8; ++k8) { \
        rw[k8*4+0] = BUF[k8].x; rw[k8*4+1] = BUF[k8].y; \
        rw[k8*4+2] = BUF[k8].z; rw[k8*4+3] = BUF[k8].w; } \
    uint32_t keptmask = 0; \
    if (lane == (CC)) { \
        uint32_t myrem = removed; \
        _Pragma("unroll") for (int b = 0; b < 32; ++b) { \
            if (!((myrem >> b) & 1u)) { keptmask |= (1u << b); myrem |= rw[b]; } } } \
    keptmask = __shfl(keptmask, (CC), 64); \
    _Pragma("unroll") for (int b = 0; b < 32; ++b) \
        if ((keptmask >> b) & 1u) removed |= rw[b]; \
} while (0)

__global__ void __launch_bounds__(64)
nms_kernel(const uint32_t* __restrict__ MT, const float* __restrict__ sel_score,
           const float* __restrict__ det_cand, float* __restrict__ det) {
    int lane = threadIdx.x;
    uint32_t removed = 0;
    for (int b = 0; b < 32; ++b)
        if (!(sel_score[lane * 32 + b] > CONF_T)) removed |= (1u << b);

    const uint4* mbase = (const uint4*)(MT + (size_t)lane * 2048);
    uint4 A[8], B[8], C[8], D[8];
    NMS_LOAD(A, 0); NMS_LOAD(B, 1); NMS_LOAD(C, 2);
    for (int c = 0; c < 64; c += 4) {
        NMS_LOAD(D, c + 3);
        NMS_PROC(A, c);
        if (c + 4 < 64) NMS_LOAD(A, c + 4);
        NMS_PROC(B, c + 1);
        if (c + 5 < 64) NMS_LOAD(B, c + 5);
        NMS_PROC(C, c + 2);
        if (c + 6 < 64) NMS_LOAD(C, c + 6);
        NMS_PROC(D, c + 3);
    }

    uint32_t kw = ~removed;
    int cnt = __popc(kw);
    int pre = cnt;
    for (int o = 1; o < 64; o <<= 1) {
        int n = __shfl_up(pre, o, 64);
        if (lane >= o) pre += n;
    }
    int excl = pre - cnt;
    int total = __shfl(pre, 63, 64);

    int r = excl;
    for (int b = 0; b < 32; ++b) {
        if ((kw >> b) & 1u) {
            if (r < MAXDET) {
                const float* src = det_cand + (size_t)(lane * 32 + b) * 6;
                float* dst = det + (size_t)r * 6;
                for (int j = 0; j < 6; ++j) dst[j] = src[j];
            }
            ++r;
        }
    }
    int start = total < MAXDET ? total : MAXDET;
    for (int z = start + lane; z < MAXDET; z += 64) {
        float* dst = det + (size_t)z * 6;
        for (int j = 0; j < 6; ++j) dst[j] = 0.0f;
    }
}

// ----------------------------------------------------------------- launcher
extern "C" void kernel_launch(void* const* d_in, const int* in_sizes, int n_in,
                              void* d_out, int out_size, void* d_ws, size_t ws_size,
                              hipStream_t stream) {
    const int*   img  = (const int*)d_in[0];
    const float* pred = (const float*)d_in[1];   // (8, 25200, 85); only batch 0 used
    float* out = (float*)d_out;                  // det[1000*6] then x[3*640*640]
    char* ws = (char*)d_ws;

    uint32_t* keys      = (uint32_t*)(ws + WS_KEYS);
    int*      cls       = (int*)(ws + WS_CLS);
    float*    sel_score = (float*)(ws + WS_SELSCORE);
    float4*   selbox    = (float4*)(ws + WS_SELBOX);
    float*    det_cand  = (float*)(ws + WS_DETCAND);
    uint32_t* MT        = (uint32_t*)(ws + WS_MASK);
    uint32_t* ghist     = (uint32_t*)(ws + WS_HIST);   // aliases MT[0..512) — safe

    img_kernel<<<(640 * 640 * 3 + 255) / 256, 256, 0, stream>>>(img, out + MAXDET * 6, ghist);
    score_kernel<<<(N_ANCH + 255) / 256, 256, 0, stream>>>(pred, keys, cls, ghist);
    rank_kernel<<<NB_RANK, 256, 0, stream>>>(keys, pred, cls, ghist, sel_score, selbox, det_cand);
    mask_kernel<<<(KSEL * 64) / 256, 256, 0, stream>>>(selbox, MT);
    nms_kernel<<<1, 64, 0, stream>>>(MT, sel_score, det_cand, out);
}

// Round 4
// 207.611 us; speedup vs baseline: 1.6680x; 1.6680x over previous
//
#include <hip/hip_runtime.h>
#include <stdint.h>

#define N_ANCH 25200
#define NCLS   80
#define KSEL   2048
#define MAXDET 1000
#define CONF_T 0.4f
#define IOU_T  0.45f
#define MAX_WH 7680.0f
#define HBINS  512
#define HBASE  0xBE00u
#define NSB    788               // score blocks: 32 anchors each
#define NIB    1200              // img blocks: 1024 px-channels each
#define NCAND_MAX 4096

// workspace byte offsets (total 819200 B)
#define WS_KEYS      0          // uint32 [25200]
#define WS_CLS       102400     // int32  [25200]
#define WS_SELSCORE  204800     // float  [2048]
#define WS_SELBOX    212992     // float4 [2048]
#define WS_DETCAND   245760     // float  [2048*6]
#define WS_MASK      294912     // uint32 MT[64][2048] (written by mask AFTER the
                                // aliased ghist/cnt/cand below are consumed)
#define WS_HIST      294912     // uint32 [512]
#define WS_CNT       296960     // uint32 [1]
#define WS_CAND      296976     // u64 [4096] (8-aligned), ends 329744 < 819200

// ---------------------------------------------------------------- prep kernel
// blocks [0,NSB): score role — 8 lanes per anchor, interleaved class loads,
//   3-step shuffle argmax (exact product compare, first-occurrence ties).
// blocks [NSB,NSB+NIB): img role — float4 writes, x[c][p] = img[p][2-c]/255.
__global__ void __launch_bounds__(256)
prep_kernel(const float* __restrict__ pred0, const int* __restrict__ img,
            float* __restrict__ xout, uint32_t* __restrict__ keys,
            int* __restrict__ cls, uint32_t* __restrict__ ghist) {
    int blk = blockIdx.x;
    int tid = threadIdx.x;
    if (blk < NSB) {
        int lane = tid & 63, wave = tid >> 6;
        int g = lane >> 3, l = lane & 7;
        int a = blk * 32 + wave * 8 + g;
        if (a >= N_ANCH) return;
        const float* p = pred0 + (size_t)a * 85;
        float obj = p[4];
        float v = -1e30f; int ci = 0;
        #pragma unroll
        for (int k = 0; k < 10; ++k) {
            int c = l + 8 * k;               // classes covered: exactly 0..79
            float x = p[5 + c] * obj;        // exact product compare (matches ref)
            if (x > v) { v = x; ci = c; }    // within-lane: increasing c, > = first
        }
        #pragma unroll
        for (int m = 1; m < 8; m <<= 1) {    // reduce across the 8-lane group
            float ov = __shfl_xor(v, m, 64);
            int   oc = __shfl_xor(ci, m, 64);
            if (ov > v || (ov == v && oc < ci)) { v = ov; ci = oc; }
        }
        if (l == 0) {
            float score = (v > CONF_T) ? v : -1.0f;
            uint32_t bits = __float_as_uint(score);
            uint32_t key = (bits & 0x80000000u) ? ~bits : (bits | 0x80000000u);
            keys[a] = key; cls[a] = ci;
            if (key >= (HBASE << 16)) atomicAdd(&ghist[(key >> 16) - HBASE], 1u);
        }
    } else {
        int b = blk - NSB;
        int i4 = b * 1024 + tid * 4;         // < 1,228,800 exactly
        int c = i4 / 409600;
        int rem = i4 - c * 409600;
        int ch = 2 - c;
        float4 o;
        o.x = (float)img[(rem + 0) * 3 + ch] / 255.0f;
        o.y = (float)img[(rem + 1) * 3 + ch] / 255.0f;
        o.z = (float)img[(rem + 2) * 3 + ch] / 255.0f;
        o.w = (float)img[(rem + 3) * 3 + ch] / 255.0f;
        *(float4*)(xout + i4) = o;
    }
}

// ------------------------------------------------------------- compact kernel
// 25 blocks. Each: hist suffix-scan -> lim; scan its key slice (1 uint4/thr),
// append (key,~idx) packs to global cand list (wave-coalesced atomics).
__global__ void __launch_bounds__(256)
compact_kernel(const uint32_t* __restrict__ keys, const uint32_t* __restrict__ ghist,
               uint32_t* __restrict__ cnt, unsigned long long* __restrict__ cand) {
    __shared__ uint32_t h[HBINS];
    __shared__ uint32_t s_lim;
    int tid = threadIdx.x;
    h[tid] = ghist[tid]; h[tid + 256] = ghist[tid + 256];
    if (tid == 0) s_lim = (HBASE << 16);
    __syncthreads();
    for (int off = 1; off < HBINS; off <<= 1) {
        uint32_t a0 = h[tid] + ((tid + off < HBINS) ? h[tid + off] : 0u);
        uint32_t a1 = h[tid + 256] + ((tid + 256 + off < HBINS) ? h[tid + 256 + off] : 0u);
        __syncthreads();
        h[tid] = a0; h[tid + 256] = a1;
        __syncthreads();
    }
    for (int b = tid; b < HBINS; b += 256) {
        uint32_t sb  = h[b];
        uint32_t sb1 = (b < HBINS - 1) ? h[b + 1] : 0u;
        if (sb >= KSEL && sb1 < KSEL) s_lim = (uint32_t)(HBASE + b) << 16;
    }
    __syncthreads();
    uint32_t lim = s_lim;
    int i = blockIdx.x * 256 + tid;          // uint4 index, 6300 total
    if (i < N_ANCH / 4) {
        uint4 kk = ((const uint4*)keys)[i];
        uint32_t ks[4] = {kk.x, kk.y, kk.z, kk.w};
        #pragma unroll
        for (int j = 0; j < 4; ++j) {
            if (ks[j] >= lim) {
                uint32_t p = atomicAdd(cnt, 1u);
                if (p < NCAND_MAX)
                    cand[p] = ((unsigned long long)ks[j] << 32)
                            | (uint32_t)(~(uint32_t)(i * 4 + j));
            }
        }
    }
}

// ---------------------------------------------------------------- rank kernel
// 128 blocks x 256 thr; 32 items/block, 8 threads/item. rank = #{pack > mine}
// via throughput-bound independent LDS reads. Ranks are a total order (idx
// breaks ties) -> every slot 0..2047 written exactly once. Emit at pos=rank.
__global__ void __launch_bounds__(256)
rank_kernel(const uint32_t* __restrict__ cnt, const unsigned long long* __restrict__ cand,
            const float* __restrict__ pred0, const int* __restrict__ cls,
            float* __restrict__ sel_score, float4* __restrict__ selbox,
            float* __restrict__ det_cand) {
    __shared__ unsigned long long s_it[NCAND_MAX];
    __shared__ int s_n;
    int tid = threadIdx.x;
    if (tid == 0) s_n = (int)min(*cnt, (uint32_t)NCAND_MAX);
    __syncthreads();
    int n = s_n;
    int base = blockIdx.x * 32;
    if (base >= n) return;
    for (int i = tid; i < n; i += 256) s_it[i] = cand[i];
    __syncthreads();
    int it = base + (tid >> 3);
    int sl = tid & 7;
    if (it >= n) return;                      // whole 8-lane group exits together
    unsigned long long mine = s_it[it];
    int c = 0;
    for (int t = sl; t < n; t += 8)           // independent reads, pipelined
        c += (s_it[t] > mine) ? 1 : 0;
    #pragma unroll
    for (int m = 1; m < 8; m <<= 1) c += __shfl_xor(c, m, 64);
    if (sl == 0 && c < KSEL) {
        uint32_t key = (uint32_t)(mine >> 32);
        int ai = (int)(~(uint32_t)mine);
        uint32_t fb = (key & 0x80000000u) ? (key & 0x7FFFFFFFu) : ~key;
        float score = __uint_as_float(fb);
        const float* p = pred0 + (size_t)ai * 85;
        float x = p[0], y = p[1], w = p[2], hh = p[3];
        float x1 = x - w * 0.5f, y1 = y - hh * 0.5f;
        float x2 = x + w * 0.5f, y2 = y + hh * 0.5f;
        float cf = (float)cls[ai];
        float off = cf * MAX_WH;
        selbox[c] = make_float4(x1 + off, y1 + off, x2 + off, y2 + off);
        float* dc = det_cand + (size_t)c * 6;
        dc[0] = x1; dc[1] = y1; dc[2] = x2; dc[3] = y2; dc[4] = score; dc[5] = cf;
        sel_score[c] = score;
    }
}

// ---------------------------------------------------------------- mask kernel
// Transposed MT[w][row]: coalesced writes; sx[row] stride-1 (2-way, free),
// sx[j] broadcast (free).
__global__ void __launch_bounds__(256)
mask_kernel(const float4* __restrict__ selbox, uint32_t* __restrict__ MT) {
    __shared__ float sx1[KSEL], sy1[KSEL], sx2[KSEL], sy2[KSEL];
    for (int i = threadIdx.x; i < KSEL; i += 256) {
        float4 b = selbox[i];
        sx1[i] = b.x; sy1[i] = b.y; sx2[i] = b.z; sy2[i] = b.w;
    }
    __syncthreads();
    int t = blockIdx.x * 256 + threadIdx.x;
    int row = t & 2047;
    int w   = t >> 11;
    float ax1 = sx1[row], ay1 = sy1[row], ax2 = sx2[row], ay2 = sy2[row];
    float areaA = (ax2 - ax1) * (ay2 - ay1);
    uint32_t bits = 0;
    int jbase = w * 32;
    for (int b = 0; b < 32; ++b) {
        int j = jbase + b;
        if (j > row) {
            float bx1 = sx1[j], by1 = sy1[j], bx2 = sx2[j], by2 = sy2[j];
            float lx = fmaxf(ax1, bx1), ly = fmaxf(ay1, by1);
            float rx = fminf(ax2, bx2), ry = fminf(ay2, by2);
            float ww = fmaxf(rx - lx, 0.0f), hh = fmaxf(ry - ly, 0.0f);
            float inter = ww * hh;
            float areaB = (bx2 - bx1) * (by2 - by1);
            float iou = inter / (areaA + areaB - inter + 1e-7f);
            if (iou > IOU_T) bits |= (1u << b);
        }
    }
    MT[t] = bits;   // t == w*2048 + row
}

// ----------------------------------------------------------------- nms kernel
// One wave; lane l owns keep-bits for rows [32l,32l+32). Chunk c: 8 coalesced
// uint4 loads per lane; simple 2-buffer prefetch (no spill).
__global__ void __launch_bounds__(64)
nms_kernel(const uint32_t* __restrict__ MT, const float* __restrict__ sel_score,
           const float* __restrict__ det_cand, float* __restrict__ det) {
    int lane = threadIdx.x;
    uint32_t removed = 0;
    #pragma unroll
    for (int b = 0; b < 32; ++b)
        if (!(sel_score[lane * 32 + b] > CONF_T)) removed |= (1u << b);

    const uint4* mbase = (const uint4*)(MT + (size_t)lane * 2048);
    uint4 cur[8], nxt[8];
    #pragma unroll
    for (int k = 0; k < 8; ++k) cur[k] = mbase[k];
    for (int c = 0; c < 64; ++c) {
        if (c + 1 < 64) {
            #pragma unroll
            for (int k = 0; k < 8; ++k) nxt[k] = mbase[(c + 1) * 8 + k];
        }
        uint32_t rw[32];
        #pragma unroll
        for (int k = 0; k < 8; ++k) {
            rw[4*k] = cur[k].x; rw[4*k+1] = cur[k].y;
            rw[4*k+2] = cur[k].z; rw[4*k+3] = cur[k].w;
        }
        uint32_t keptmask = 0;
        if (lane == c) {
            uint32_t myrem = removed;
            #pragma unroll
            for (int b = 0; b < 32; ++b)
                if (!((myrem >> b) & 1u)) { keptmask |= (1u << b); myrem |= rw[b]; }
        }
        keptmask = __shfl(keptmask, c, 64);
        #pragma unroll
        for (int b = 0; b < 32; ++b)
            if ((keptmask >> b) & 1u) removed |= rw[b];
        #pragma unroll
        for (int k = 0; k < 8; ++k) cur[k] = nxt[k];
    }

    uint32_t kw = ~removed;
    int cnt2 = __popc(kw);
    int pre = cnt2;
    for (int o = 1; o < 64; o <<= 1) {
        int v = __shfl_up(pre, o, 64);
        if (lane >= o) pre += v;
    }
    int excl = pre - cnt2;
    int total = __shfl(pre, 63, 64);

    int r = excl;
    for (int b = 0; b < 32; ++b) {
        if ((kw >> b) & 1u) {
            if (r < MAXDET) {
                const float* src = det_cand + (size_t)(lane * 32 + b) * 6;
                float* dst = det + (size_t)r * 6;
                for (int j = 0; j < 6; ++j) dst[j] = src[j];
            }
            ++r;
        }
    }
    int start = total < MAXDET ? total : MAXDET;
    for (int z = start + lane; z < MAXDET; z += 64) {
        float* dst = det + (size_t)z * 6;
        for (int j = 0; j < 6; ++j) dst[j] = 0.0f;
    }
}

// ------------------------------------------------------------------ launcher
extern "C" void kernel_launch(void* const* d_in, const int* in_sizes, int n_in,
                              void* d_out, int out_size, void* d_ws, size_t ws_size,
                              hipStream_t stream) {
    const int*   img  = (const int*)d_in[0];
    const float* pred = (const float*)d_in[1];   // (8,25200,85); only batch 0 used
    float* out = (float*)d_out;                  // det[1000*6] then x[3*640*640]
    char* ws = (char*)d_ws;

    uint32_t* keys      = (uint32_t*)(ws + WS_KEYS);
    int*      cls       = (int*)(ws + WS_CLS);
    float*    sel_score = (float*)(ws + WS_SELSCORE);
    float4*   selbox    = (float4*)(ws + WS_SELBOX);
    float*    det_cand  = (float*)(ws + WS_DETCAND);
    uint32_t* MT        = (uint32_t*)(ws + WS_MASK);
    uint32_t* ghist     = (uint32_t*)(ws + WS_HIST);
    uint32_t* cnt       = (uint32_t*)(ws + WS_CNT);
    unsigned long long* cand = (unsigned long long*)(ws + WS_CAND);

    hipMemsetAsync(ghist, 0, 2064, stream);      // ghist[512] + cnt
    prep_kernel<<<NSB + NIB, 256, 0, stream>>>(pred, img, out + MAXDET * 6, keys, cls, ghist);
    compact_kernel<<<25, 256, 0, stream>>>(keys, ghist, cnt, cand);
    rank_kernel<<<NCAND_MAX / 32, 256, 0, stream>>>(cnt, cand, pred, cls,
                                                    sel_score, selbox, det_cand);
    mask_kernel<<<(KSEL * 64) / 256, 256, 0, stream>>>(selbox, MT);
    nms_kernel<<<1, 64, 0, stream>>>(MT, sel_score, det_cand, out);
}